// Round 1
// 2369.135 us; speedup vs baseline: 1.3089x; 1.3089x over previous
//
#include <hip/hip_runtime.h>

#define DM    2048
#define DFF   8192
#define NH    16
#define DKH   128
#define BB    128
#define SS    128
#define MROWS (BB*SS)   // 16384

typedef __bf16 bf16;
using bf16x8v = __attribute__((ext_vector_type(8))) __bf16;
using bf16x4v = __attribute__((ext_vector_type(4))) __bf16;
using f32x4   = __attribute__((ext_vector_type(4))) float;

__device__ __forceinline__ f32x4 mfma16(bf16x8v a, bf16x8v b, f32x4 c) {
  return __builtin_amdgcn_mfma_f32_16x16x32_bf16(a, b, c, 0, 0, 0);
}

__device__ __forceinline__ void async16(const void* g, void* l) {
  __builtin_amdgcn_global_load_lds(
      (const __attribute__((address_space(1))) void*)g,
      (__attribute__((address_space(3))) void*)l, 16, 0, 0);
}

// ---------------------------------------------------------------- casts
__global__ __launch_bounds__(256) void cast_bf16_kernel(const float* __restrict__ in,
                                                        bf16* __restrict__ out) {
  size_t i = ((size_t)blockIdx.x * 256 + threadIdx.x) * 4;
  float4 v = *(const float4*)(in + i);
  bf16x4v o = { (bf16)v.x, (bf16)v.y, (bf16)v.z, (bf16)v.w };
  *(bf16x4v*)(out + i) = o;
}

// in: fp32 [R][C]  ->  out: bf16 [C][R]
__global__ __launch_bounds__(256) void transpose_cast_kernel(const float* __restrict__ in,
                                                             bf16* __restrict__ out,
                                                             int R, int C) {
  __shared__ float tile[32][33];
  int c0 = blockIdx.x * 32, r0 = blockIdx.y * 32;
  int tx = threadIdx.x & 31;
  int ty = threadIdx.x >> 5;  // 0..7
  #pragma unroll
  for (int i = ty; i < 32; i += 8)
    tile[i][tx] = in[(size_t)(r0 + i) * C + c0 + tx];
  __syncthreads();
  #pragma unroll
  for (int i = ty; i < 32; i += 8)
    out[(size_t)(c0 + i) * R + r0 + tx] = (bf16)tile[tx][i];
}

// ---------------------------------------------------------------- GEMM
// 256x256 tile, BK=64, 512 thr (8 waves, 2Mx4N), 8-phase double-buffered
// schedule (T1 XCD swizzle + T2 both-sides chunk^row swizzle + T3/T4 counted
// vmcnt + T5 setprio).  Requires M%256==0, N%256==0, K%128==0.
// out[M][N] = A[M][K] @ Bt[N][K]^T + bias (+ resid), epilogue optional GELU.
//
// LDS map (bf16 elements), per dbuf of 32768 el (64 KiB):
//   A half0 @ 0, A half1 @ 8192, B half0 @ 16384, B half1 @ 24576.
// Within a half [128 rows][64 cols]: element off = r*64 + (chunk^(r&7))*8 + j
// (chunk = col/8).  global_load_lds dest is LINEAR (idx*16B); the SOURCE
// chunk is inverse-permuted, and reads apply the same involution (rule #21).
//
// Issue schedule (tile t, quadrant q):  q0: A0(t+1)  q1: A1(t+1)
//   q2: B0(t+2)  q3: B1(t+2).  Slot-free proofs:
//   A(t+1) -> buf^1, whose A was last read at (t-1).q3 (barrier before q0).
//   B(t+2) -> buf,  whose B was last read at (t).q0 (barrier before q2).
// vmcnt(4) at q3 leaves exactly {B0,B1(t+2)} in flight and guarantees all of
// tile t+1 resident before (t+1).q0 reads (4 loads = 2 half-tiles pipelined
// across the barrier; never drains to 0 in steady state).
__global__ __launch_bounds__(512, 2) void gemm_bt_kernel(
    const bf16* __restrict__ A, const bf16* __restrict__ Bt,
    const float* __restrict__ bias, const bf16* __restrict__ resid,
    bf16* __restrict__ Cb, float* __restrict__ Cf,
    int M, int N, int K, int do_gelu)
{
  __shared__ __align__(16) bf16 smem[2 * 32768];   // 128 KiB

  const int tid  = threadIdx.x;
  const int lane = tid & 63;
  const int wave = tid >> 6;        // 0..7
  const int wm   = wave >> 2;       // 0..1  M half
  const int wn   = wave & 3;        // 0..3  N quarter
  const int lr   = lane & 15;
  const int lq   = lane >> 4;       // 0..3
  const int x7   = lr & 7;          // read-side swizzle key (rowlow3 == lr&7)

  // T1: bijective XCD-aware block swizzle (m204)
  const int nwg = gridDim.x;
  const int nbx = N >> 8;
  int swz;
  {
    int qq = nwg >> 3, rr = nwg & 7;
    int xcd = blockIdx.x & 7, loc = blockIdx.x >> 3;
    swz = (xcd < rr ? xcd * (qq + 1) : rr * (qq + 1) + (xcd - rr) * qq) + loc;
  }
  const int bm = swz / nbx, bn = swz % nbx;
  const int NT = K >> 6;            // K-tiles of 64 (even, K%128==0)

  // staging precompute: per thread, 2 chunks per half-tile.
  // chunk idx = ld*512+tid; r = idx>>3 (row in half), linear LDS dest idx*16B;
  // source chunk = (idx&7) ^ (r&7)  (inverse swizzle).
  const bf16* aptr[2];
  const bf16* bptr[2];
  int ldsoff[2];
  #pragma unroll
  for (int ld = 0; ld < 2; ++ld) {
    int idx = ld * 512 + tid;          // 0..1023
    int r   = idx >> 3;                // 0..127
    int ch  = (idx & 7) ^ (r & 7);     // pre-swizzled source chunk
    aptr[ld]   = A  + (size_t)(bm * 256 + r) * K + ch * 8;
    bptr[ld]   = Bt + (size_t)(bn * 256 + r) * K + ch * 8;
    ldsoff[ld] = idx * 8;
  }

  auto stageA = [&](int buf, int h, int u) {
    #pragma unroll
    for (int ld = 0; ld < 2; ++ld)
      async16(aptr[ld] + (size_t)h * 128 * K + u * 64,
              smem + buf * 32768 + h * 8192 + ldsoff[ld]);
  };
  auto stageB = [&](int buf, int h, int u) {
    #pragma unroll
    for (int ld = 0; ld < 2; ++ld)
      async16(bptr[ld] + (size_t)h * 128 * K + u * 64,
              smem + buf * 32768 + 16384 + h * 8192 + ldsoff[ld]);
  };

  // fragment read offsets within a half (elements); both ks variants.
  int aoff[2];
  #pragma unroll
  for (int ks = 0; ks < 2; ++ks)
    aoff[ks] = lr * 64 + (((ks * 4 + lq) ^ x7) * 8);

  const bf16* Abase = smem + wm * 8192;
  const bf16* Bbase = smem + 16384 + (wn >> 1) * 8192 + (wn & 1) * 4096;

  f32x4 acc[8][4];
  #pragma unroll
  for (int i = 0; i < 8; i++)
    #pragma unroll
    for (int j = 0; j < 4; j++) acc[i][j] = (f32x4){0.f, 0.f, 0.f, 0.f};

  // ---- prologue: tile0 (A0,A1,B0,B1) + tile1 (B0,B1); drain to tile0 only.
  stageA(0, 0, 0); stageA(0, 1, 0);
  stageB(0, 0, 0); stageB(0, 1, 0);
  stageB(1, 0, 1); stageB(1, 1, 1);
  asm volatile("s_waitcnt vmcnt(4)" ::: "memory");
  __builtin_amdgcn_s_barrier();

  // ---- main loop: 4 phases per K-tile
  for (int t = 0; t < NT; ++t) {
    const int buf = t & 1;
    const bf16* At  = Abase + buf * 32768;
    const bf16* Btl = Bbase + buf * 32768;
    bf16x8v bfrag[4][2];
    #pragma unroll
    for (int q = 0; q < 4; ++q) {
      // ds-reads for this phase (B frags once per tile, in q0)
      if (q == 0) {
        #pragma unroll
        for (int fj = 0; fj < 4; ++fj)
          #pragma unroll
          for (int ks = 0; ks < 2; ++ks)
            bfrag[fj][ks] = *(const bf16x8v*)(Btl + fj * 1024 + aoff[ks]);
      }
      bf16x8v afr[2][2];
      #pragma unroll
      for (int f2 = 0; f2 < 2; ++f2)
        #pragma unroll
        for (int ks = 0; ks < 2; ++ks)
          afr[f2][ks] = *(const bf16x8v*)(At + (q * 2 + f2) * 1024 + aoff[ks]);

      // one half-tile prefetch per phase
      if (q == 0)      { if (t + 1 < NT) stageA(buf ^ 1, 0, t + 1); }
      else if (q == 1) { if (t + 1 < NT) stageA(buf ^ 1, 1, t + 1); }
      else if (q == 2) { if (t + 2 < NT) stageB(buf,     0, t + 2); }
      else             { if (t + 2 < NT) stageB(buf,     1, t + 2); }

      if (q == 0) asm volatile("s_waitcnt lgkmcnt(8)" ::: "memory");
      __builtin_amdgcn_s_barrier();
      asm volatile("s_waitcnt lgkmcnt(0)" ::: "memory");
      __builtin_amdgcn_sched_barrier(0);
      __builtin_amdgcn_s_setprio(1);
      #pragma unroll
      for (int f2 = 0; f2 < 2; ++f2)
        #pragma unroll
        for (int fj = 0; fj < 4; ++fj)
          #pragma unroll
          for (int ks = 0; ks < 2; ++ks)
            acc[q * 2 + f2][fj] = mfma16(afr[f2][ks], bfrag[fj][ks],
                                         acc[q * 2 + f2][fj]);
      __builtin_amdgcn_s_setprio(0);
      if (q == 3) {
        if (t < NT - 2)       asm volatile("s_waitcnt vmcnt(4)" ::: "memory");
        else if (t == NT - 2) asm volatile("s_waitcnt vmcnt(0)" ::: "memory");
      }
      __builtin_amdgcn_s_barrier();
    }
  }

  // ---- epilogue
  const int row0 = bm * 256 + wm * 128 + lq * 4;
  const int col0 = bn * 256 + wn * 64 + lr;
  #pragma unroll
  for (int fj = 0; fj < 4; ++fj) {
    const int col = col0 + fj * 16;
    const float bv = bias[col];
    #pragma unroll
    for (int fi = 0; fi < 8; ++fi) {
      #pragma unroll
      for (int r = 0; r < 4; ++r) {
        const int row = row0 + fi * 16 + r;
        float v = acc[fi][fj][r] + bv;
        if (do_gelu) v = 0.5f * v * (1.0f + erff(v * 0.70710678118654752f));
        if (resid)   v += (float)resid[(size_t)row * N + col];
        if (Cf) Cf[(size_t)row * N + col] = v;
        else    Cb[(size_t)row * N + col] = (bf16)v;
      }
    }
  }
}

// ---------------------------------------------------------------- attention
// one block (256 thr, 4 waves) per (b,h).  scores[b,h,i,j] =
//   (Q.K^T)/sqrt(128) + rel_emb[(b-i) mod 512][j]  (reference broadcast quirk)
#define SMS 136  // padded LDS stride: 272 B = 17*16 -> b128-aligned, 2-way banks (free)

__global__ __launch_bounds__(256) void attn_kernel(
    const bf16* __restrict__ Q, const bf16* __restrict__ K,
    const bf16* __restrict__ V, const float* __restrict__ rel,
    bf16* __restrict__ ctx)
{
  __shared__ __align__(16) bf16 smem[192 * SMS];      // 52224 B
  bf16* Ks = smem;                                    // [128][SMS] phase 1
  bf16* Ps = smem;                                    // [128][SMS] phase 2 (aliases Ks)
  bf16* VT = smem + 128 * SMS;                        // [64][SMS]  phase 2

  const int tid  = threadIdx.x;
  const int lane = tid & 63, wave = tid >> 6;
  const int lr = lane & 15, lq = lane >> 4, lk = lq * 8;
  const int bh = blockIdx.x;
  const int b = bh >> 4, h = bh & 15;
  const size_t base = (size_t)b * SS * DM + (size_t)h * DKH;

  // stage K [j][d]
  #pragma unroll
  for (int p = 0; p < 8; p++) {
    int idx = p * 256 + tid;
    int row = idx >> 4;
    int col = (idx & 15) * 8;
    *(int4*)(Ks + row * SMS + col) = *(const int4*)(K + base + (size_t)row * DM + col);
  }
  // Q fragments straight from global
  bf16x8v qf[2][4];
  #pragma unroll
  for (int mt = 0; mt < 2; mt++)
    #pragma unroll
    for (int ks = 0; ks < 4; ks++)
      qf[mt][ks] = *(const bf16x8v*)(Q + base + (size_t)(wave*32 + mt*16 + lr) * DM + ks*32 + lk);

  __syncthreads();

  f32x4 sc[2][8];
  #pragma unroll
  for (int mt = 0; mt < 2; mt++)
    #pragma unroll
    for (int nt = 0; nt < 8; nt++) sc[mt][nt] = (f32x4){0.f, 0.f, 0.f, 0.f};

  #pragma unroll
  for (int ks = 0; ks < 4; ks++) {
    #pragma unroll
    for (int nt = 0; nt < 8; nt++) {
      bf16x8v kf = *(const bf16x8v*)(Ks + (nt*16 + lr) * SMS + ks*32 + lk);
      sc[0][nt] = mfma16(qf[0][ks], kf, sc[0][nt]);
      sc[1][nt] = mfma16(qf[1][ks], kf, sc[1][nt]);
    }
  }
  __syncthreads();   // all waves done reading Ks; Ps region may be overwritten

  const float scale = 0.08838834764831845f;  // 1/sqrt(128)
  #pragma unroll
  for (int mt = 0; mt < 2; mt++) {
    #pragma unroll
    for (int r = 0; r < 4; r++) {
      int i = wave * 32 + mt * 16 + lq * 4 + r;
      int dmi = b - i; if (dmi < 0) dmi += 512;
      const float* relrow = rel + (size_t)dmi * DKH + lr;
      float vv[8];
      float mx = -1e30f;
      #pragma unroll
      for (int nt = 0; nt < 8; nt++) {
        float v = sc[mt][nt][r] * scale + relrow[nt * 16];
        vv[nt] = v;
        mx = fmaxf(mx, v);
      }
      #pragma unroll
      for (int m = 1; m < 16; m <<= 1) mx = fmaxf(mx, __shfl_xor(mx, m));
      float sum = 0.f;
      #pragma unroll
      for (int nt = 0; nt < 8; nt++) { vv[nt] = __expf(vv[nt] - mx); sum += vv[nt]; }
      #pragma unroll
      for (int m = 1; m < 16; m <<= 1) sum += __shfl_xor(sum, m);
      float inv = 1.f / sum;
      #pragma unroll
      for (int nt = 0; nt < 8; nt++)
        Ps[i * SMS + nt * 16 + lr] = (bf16)(vv[nt] * inv);
    }
  }

  #pragma unroll
  for (int half = 0; half < 2; half++) {
    __syncthreads();                       // Ps written / prev VT reads done
    const int d0 = half * 64;
    #pragma unroll
    for (int p = 0; p < 4; p++) {
      int idx = p * 256 + tid;             // 128 j x 8 chunks
      int j  = idx >> 3;
      int dc = (idx & 7) * 8;
      union { int4 i4; bf16 hh[8]; } u;
      u.i4 = *(const int4*)(V + base + (size_t)j * DM + d0 + dc);
      #pragma unroll
      for (int uu = 0; uu < 8; uu++)
        VT[(dc + uu) * SMS + j] = u.hh[uu];
    }
    __syncthreads();
    f32x4 oa[2][4];
    #pragma unroll
    for (int mt = 0; mt < 2; mt++)
      #pragma unroll
      for (int nt = 0; nt < 4; nt++) oa[mt][nt] = (f32x4){0.f, 0.f, 0.f, 0.f};
    #pragma unroll
    for (int ks = 0; ks < 4; ks++) {
      bf16x8v pf0 = *(const bf16x8v*)(Ps + (wave*32 +      lr) * SMS + ks*32 + lk);
      bf16x8v pf1 = *(const bf16x8v*)(Ps + (wave*32 + 16 + lr) * SMS + ks*32 + lk);
      #pragma unroll
      for (int nt = 0; nt < 4; nt++) {
        bf16x8v vf = *(const bf16x8v*)(VT + (nt*16 + lr) * SMS + ks*32 + lk);
        oa[0][nt] = mfma16(pf0, vf, oa[0][nt]);
        oa[1][nt] = mfma16(pf1, vf, oa[1][nt]);
      }
    }
    #pragma unroll
    for (int mt = 0; mt < 2; mt++)
      #pragma unroll
      for (int nt = 0; nt < 4; nt++)
        #pragma unroll
        for (int r = 0; r < 4; r++) {
          int i = wave * 32 + mt * 16 + lq * 4 + r;
          int d = d0 + nt * 16 + lr;
          ctx[base + (size_t)i * DM + d] = (bf16)oa[mt][nt][r];
        }
  }
}

// ---------------------------------------------------------------- LN kernels
// x1 = LN(xf + yb)*g + be  -> bf16
__global__ __launch_bounds__(256) void resid_ln1_kernel(
    const float* __restrict__ xf, const bf16* __restrict__ yb,
    const float* __restrict__ g, const float* __restrict__ be,
    bf16* __restrict__ outb)
{
  const int row = blockIdx.x;
  const int tid = threadIdx.x;
  const size_t off = (size_t)row * DM + tid * 8;
  float v[8];
  {
    float4 a = *(const float4*)(xf + off);
    float4 c = *(const float4*)(xf + off + 4);
    v[0]=a.x; v[1]=a.y; v[2]=a.z; v[3]=a.w;
    v[4]=c.x; v[5]=c.y; v[6]=c.z; v[7]=c.w;
    union { int4 i4; bf16 hh[8]; } u;
    u.i4 = *(const int4*)(yb + off);
    #pragma unroll
    for (int t = 0; t < 8; t++) v[t] += (float)u.hh[t];
  }
  float s1 = 0.f, s2 = 0.f;
  #pragma unroll
  for (int t = 0; t < 8; t++) { s1 += v[t]; s2 += v[t] * v[t]; }
  #pragma unroll
  for (int m = 1; m < 64; m <<= 1) { s1 += __shfl_xor(s1, m); s2 += __shfl_xor(s2, m); }
  __shared__ float r1[4], r2[4];
  if ((tid & 63) == 0) { r1[tid >> 6] = s1; r2[tid >> 6] = s2; }
  __syncthreads();
  s1 = r1[0] + r1[1] + r1[2] + r1[3];
  s2 = r2[0] + r2[1] + r2[2] + r2[3];
  const float mu  = s1 * (1.f / DM);
  const float var = s2 * (1.f / DM) - mu * mu;
  const float rstd = rsqrtf(var + 1e-5f);
  const int c0 = tid * 8;
  union { int4 i4; bf16 hh[8]; } w;
  #pragma unroll
  for (int t = 0; t < 8; t++)
    w.hh[t] = (bf16)((v[t] - mu) * rstd * g[c0 + t] + be[c0 + t]);
  *(int4*)(outb + off) = w.i4;
}

// out = LN(in)*g + be, in fp32 split across two half buffers, out fp32
__global__ __launch_bounds__(256) void ln_final_kernel(
    const float* __restrict__ f0, const float* __restrict__ f1,
    const float* __restrict__ g, const float* __restrict__ be,
    float* __restrict__ out)
{
  const int row = blockIdx.x;
  const int tid = threadIdx.x;
  const float* src = (row < MROWS/2) ? (f0 + (size_t)row * DM)
                                     : (f1 + (size_t)(row - MROWS/2) * DM);
  const size_t off = (size_t)tid * 8;
  float v[8];
  {
    float4 a = *(const float4*)(src + off);
    float4 c = *(const float4*)(src + off + 4);
    v[0]=a.x; v[1]=a.y; v[2]=a.z; v[3]=a.w;
    v[4]=c.x; v[5]=c.y; v[6]=c.z; v[7]=c.w;
  }
  float s1 = 0.f, s2 = 0.f;
  #pragma unroll
  for (int t = 0; t < 8; t++) { s1 += v[t]; s2 += v[t] * v[t]; }
  #pragma unroll
  for (int m = 1; m < 64; m <<= 1) { s1 += __shfl_xor(s1, m); s2 += __shfl_xor(s2, m); }
  __shared__ float r1[4], r2[4];
  if ((tid & 63) == 0) { r1[tid >> 6] = s1; r2[tid >> 6] = s2; }
  __syncthreads();
  s1 = r1[0] + r1[1] + r1[2] + r1[3];
  s2 = r2[0] + r2[1] + r2[2] + r2[3];
  const float mu  = s1 * (1.f / DM);
  const float var = s2 * (1.f / DM) - mu * mu;
  const float rstd = rsqrtf(var + 1e-5f);
  const int c0 = tid * 8;
  float o[8];
  #pragma unroll
  for (int t = 0; t < 8; t++) o[t] = (v[t] - mu) * rstd * g[c0 + t] + be[c0 + t];
  float4 o0 = {o[0],o[1],o[2],o[3]};
  float4 o1 = {o[4],o[5],o[6],o[7]};
  float* dst = out + (size_t)row * DM + tid * 8;
  *(float4*)(dst) = o0;
  *(float4*)(dst + 4) = o1;
}

// ---------------------------------------------------------------- launch
// Workspace budget: 3*NE bf16 slots (201 MB) + W1T+W2T (67 MB) = 268 MB.
// d_out (128 MiB) doubles as scratch: Q/K (phase 1) then FFN h-half (phase 3).
extern "C" void kernel_launch(void* const* d_in, const int* in_sizes, int n_in,
                              void* d_out, int out_size, void* d_ws, size_t ws_size,
                              hipStream_t stream) {
  const float* x    = (const float*)d_in[0];
  const float* Wq   = (const float*)d_in[1];
  const float* bq   = (const float*)d_in[2];
  const float* Wk   = (const float*)d_in[3];
  const float* bk   = (const float*)d_in[4];
  const float* Wv   = (const float*)d_in[5];
  const float* bv   = (const float*)d_in[6];
  const float* Wo   = (const float*)d_in[7];
  const float* bo   = (const float*)d_in[8];
  const float* rel  = (const float*)d_in[9];
  const float* g1   = (const float*)d_in[10];
  const float* be1  = (const float*)d_in[11];
  const float* W1   = (const float*)d_in[12];
  const float* b1   = (const float*)d_in[13];
  const float* W2   = (const float*)d_in[14];
  const float* b2   = (const float*)d_in[15];
  const float* g2   = (const float*)d_in[16];
  const float* be2  = (const float*)d_in[17];

  const size_t NE = (size_t)MROWS * DM;  // 33,554,432
  bf16* ws  = (bf16*)d_ws;
  bf16* p0  = ws;                         // Q -> attn-out -> f1(fp32)
  bf16* p1  = ws + NE;                    // V -> x1
  bf16* p2  = ws + 2 * NE;                // xb -> ctx -> f0(fp32)
  bf16* wT  = ws + 3 * NE;                // transposed weight A (up to DM*DFF)
  bf16* wT2 = wT + (size_t)DM * DFF;      // transposed weight B

  bf16* dQ = (bf16*)d_out;                // Q in d_out scratch
  bf16* dK = dQ + NE;                     // K in d_out scratch
  bf16* dH = (bf16*)d_out;                // FFN hidden half (8192 x 8192 bf16)
  float* f0 = (float*)p2;                 // ff+resid fp32, rows 0..8191
  float* f1 = (float*)p0;                 // ff+resid fp32, rows 8192..16383

  const int gq  = (DM / 256)  * (MROWS / 256);      // 8*64  = 512 blocks
  const int gh  = (DFF / 256) * ((MROWS/2) / 256);  // 32*32 = 1024
  const int gh2 = (DM / 256)  * ((MROWS/2) / 256);  // 8*32  = 256

  // phase 1: cast + QKV projections (weights transposed just-in-time)
  cast_bf16_kernel<<<NE / 1024, 256, 0, stream>>>(x, p2);
  transpose_cast_kernel<<<dim3(DM/32, DM/32), 256, 0, stream>>>(Wq, wT, DM, DM);
  gemm_bt_kernel<<<gq, 512, 0, stream>>>(p2, wT, bq, nullptr, dQ, nullptr, MROWS, DM, DM, 0);
  transpose_cast_kernel<<<dim3(DM/32, DM/32), 256, 0, stream>>>(Wk, wT2, DM, DM);
  gemm_bt_kernel<<<gq, 512, 0, stream>>>(p2, wT2, bk, nullptr, dK, nullptr, MROWS, DM, DM, 0);
  transpose_cast_kernel<<<dim3(DM/32, DM/32), 256, 0, stream>>>(Wv, wT, DM, DM);
  gemm_bt_kernel<<<gq, 512, 0, stream>>>(p2, wT, bv, nullptr, p1, nullptr, MROWS, DM, DM, 0);

  // phase 2: attention + out-proj + LN1
  transpose_cast_kernel<<<dim3(DM/32, DM/32), 256, 0, stream>>>(Wo, wT2, DM, DM);
  attn_kernel<<<BB * NH, 256, 0, stream>>>(dQ, dK, p1, rel, p2);   // ctx -> p2 (xb dead)
  gemm_bt_kernel<<<gq, 512, 0, stream>>>(p2, wT2, bo, nullptr, p0, nullptr, MROWS, DM, DM, 0);
  resid_ln1_kernel<<<MROWS, 256, 0, stream>>>(x, p0, g1, be1, p1); // x1 -> p1 (V dead)

  // phase 3: FFN split into two M-halves; h lives in d_out (Q/K dead)
  transpose_cast_kernel<<<dim3(DFF/32, DM/32), 256, 0, stream>>>(W1, wT, DM, DFF);   // [DFF][DM]
  transpose_cast_kernel<<<dim3(DM/32, DFF/32), 256, 0, stream>>>(W2, wT2, DFF, DM);  // [DM][DFF]
  for (int half = 0; half < 2; half++) {
    const bf16* x1h = p1 + (size_t)half * (MROWS/2) * DM;
    float*      fo  = half ? f1 : f0;
    gemm_bt_kernel<<<gh, 512, 0, stream>>>(x1h, wT, b1, nullptr, dH, nullptr,
                                           MROWS/2, DFF, DM, 1);
    gemm_bt_kernel<<<gh2, 512, 0, stream>>>(dH, wT2, b2, x1h, nullptr, fo,
                                            MROWS/2, DM, DFF, 0);
  }
  ln_final_kernel<<<MROWS, 256, 0, stream>>>(f0, f1, g2, be2, (float*)d_out);
}